// Round 5
// baseline (157.796 us; speedup 1.0000x reference)
//
#include <hip/hip_runtime.h>
#include <hip/hip_bf16.h>

typedef __attribute__((ext_vector_type(8))) short bf16x8;
typedef __attribute__((ext_vector_type(4))) float f32x4;

constexpr int SQ = 2048;
constexpr int NB = 2;
constexpr int NH = 16;
constexpr int D  = 64;
constexpr int SROW = NB * NH * D;        // 2048 floats per s step (layout s,b,h,d)
constexpr int BH   = NB * NH;            // 32 (b,h) planes
constexpr int KT = 64;                   // kv cols per tile
constexpr int LDP = 72;                  // padded LDS leading dim (shorts)
constexpr int PNT = 20;                  // P-buffer nt-stride in shorts (40 B: 8-aligned)
constexpr size_t PLANE = (size_t)SQ * D; // 131072 shorts per (b,h) plane

// scale folded into Q: 1/sqrt(64) (coeff cancels) * log2(e) so exp2() is direct
constexpr float QSCALE = 0.125f * 1.44269504088896f;

// pack two fp32 -> bf16x2 dword (round-half-up: differs from RNE only on exact
// ties, prob 2^-16). 3 VALU ops for 2 values vs ~8 for manual RNE.
__device__ __forceinline__ int pack2(float lo, float hi) {
    unsigned ul = __builtin_bit_cast(unsigned, lo) + 0x8000u;
    unsigned uh = __builtin_bit_cast(unsigned, hi) + 0x8000u;
    return __builtin_amdgcn_perm(uh, ul, 0x07060302);  // {hi.b3,hi.b2,lo.b3,lo.b2}
}

// ---------------------------------------------------------------------------
// Pre-kernel: K, V fp32 -> bf16 with layout change (amortized over ~16 re-reads)
//   Kb[bh][s][d] = bf16(K)
//   Vb[bh][d][s] = bf16(V)^T
// ---------------------------------------------------------------------------
__global__ __launch_bounds__(256)
void cvt(const float* __restrict__ K, const float* __restrict__ V,
         short* __restrict__ Kb, short* __restrict__ Vb) {
    __shared__ short Vl[64][LDP];
    const int tid = threadIdx.x;
    const int t0  = blockIdx.x * 64;
    const int bh  = blockIdx.y;
    const int r   = tid >> 2;
    const int c   = (tid & 3) * 16;

    const size_t gin  = (size_t)(t0 + r) * SROW + bh * D + c;
    const size_t gout = (size_t)bh * PLANE + (size_t)(t0 + r) * D + c;

    {   // K: convert, same layout
        const float* kp = K + gin;
        int o[8];
        #pragma unroll
        for (int i = 0; i < 8; ++i) o[i] = pack2(kp[2 * i], kp[2 * i + 1]);
        *(int4*)&Kb[gout]     = *(int4*)&o[0];
        *(int4*)&Kb[gout + 8] = *(int4*)&o[4];
    }
    {   // V: convert into LDS, transpose out
        const float* vp = V + gin;
        int o[8];
        #pragma unroll
        for (int i = 0; i < 8; ++i) o[i] = pack2(vp[2 * i], vp[2 * i + 1]);
        *(int4*)&Vl[r][c]     = *(int4*)&o[0];
        *(int4*)&Vl[r][c + 8] = *(int4*)&o[4];
    }
    __syncthreads();
    {
        const int d = tid & 63, seg = tid >> 6;
        short t[16];
        #pragma unroll
        for (int u = 0; u < 16; ++u) t[u] = Vl[seg * 16 + u][d];
        const size_t vo = (size_t)bh * PLANE + (size_t)d * SQ + t0 + seg * 16;
        *(bf16x8*)&Vb[vo]     = *(bf16x8*)&t[0];
        *(bf16x8*)&Vb[vo + 8] = *(bf16x8*)&t[8];
    }
}

// ---------------------------------------------------------------------------
// Hot kernel: LDS-staged causal flash attention, complementary q-tile pairing.
// R5 changes vs R4:
//  - S^T via operand-swapped MFMA (same fragments; A/B layouts symmetric):
//    lane then holds P[m=m16][t=nt*16+quad*4+r] -> consecutive r = consecutive
//    t, so the P C->A transpose writes are 4x b64 per strip (was 16x b16).
//  - log2(e) folded into Q scale (no per-score multiply).
//  - bf16 packing via v_perm_b32 (1.5 VALU/value vs 4).
// ---------------------------------------------------------------------------
__global__ __launch_bounds__(256, 2)
void attn_fwd(const float* __restrict__ Q, const short* __restrict__ Kb,
              const short* __restrict__ Vb, float* __restrict__ Out) {
    __shared__ short Kl[KT][LDP];           // K[t][d]
    __shared__ short Vt[D][LDP];            // V^T[d][t]
    __shared__ short Pl[4][2][16][4 * PNT]; // [wave][strip][m][nt*PNT + t%16]

    const int tid  = threadIdx.x;
    const int wave = tid >> 6;
    const int m16  = tid & 15;
    const int quad = (tid & 63) >> 4;

    // decode: CU c gets blocks c (a = c%16) and c+256 (a = 15 - c%16)
    // -> per-CU iteration total is a constant 49
    const int x    = blockIdx.x;
    const int pr   = x & 255;
    const int half = x >> 8;
    const int bh   = (pr >> 4) | (half << 4);
    const int ta   = half ? (15 - (pr & 15)) : (pr & 15);
    const int tb   = 31 - ta;
    const size_t plane = (size_t)bh * PLANE;

    // ---- Q fragments (fp32 -> bf16, scale = 1/8 * log2e) ----
    bf16x8 qA[2], qB[2];
    #pragma unroll
    for (int s = 0; s < 2; ++s) {
        const int tile = s ? tb : ta;
        const float* qp = Q + (size_t)(tile * 64 + wave * 16 + m16) * SROW
                            + bh * D + quad * 8;
        #pragma unroll
        for (int ks = 0; ks < 2; ++ks) {
            float4 x0 = *(const float4*)(qp + ks * 32);
            float4 x1 = *(const float4*)(qp + ks * 32 + 4);
            int o[4];
            o[0] = pack2(x0.x * QSCALE, x0.y * QSCALE);
            o[1] = pack2(x0.z * QSCALE, x0.w * QSCALE);
            o[2] = pack2(x1.x * QSCALE, x1.y * QSCALE);
            o[3] = pack2(x1.z * QSCALE, x1.w * QSCALE);
            bf16x8 f = *(bf16x8*)&o[0];
            if (s) qB[ks] = f; else qA[ks] = f;
        }
    }

    const short* kb = Kb + plane;
    const short* vb = Vb + plane;

    // staging: thread owns 2 b128 chunks of K and 2 of V per tile
    const int kr0 = tid >> 3;            // rows 0..31
    const int kc0 = (tid & 7) * 8;
    bf16x8 rK[2], rV[2];
    auto loadTile = [&](int t0) {
        const short* kt = kb + (size_t)t0 * D;
        rK[0] = *(const bf16x8*)(kt + (size_t)kr0 * D + kc0);
        rK[1] = *(const bf16x8*)(kt + (size_t)(kr0 + 32) * D + kc0);
        const short* vt = vb + t0;
        rV[0] = *(const bf16x8*)(vt + (size_t)kr0 * SQ + kc0);
        rV[1] = *(const bf16x8*)(vt + (size_t)(kr0 + 32) * SQ + kc0);
    };

    f32x4 oA[4], oB[4], lA, lB;
    #pragma unroll
    for (int dt = 0; dt < 4; ++dt) {
        oA[dt] = f32x4{0.f, 0.f, 0.f, 0.f};
        oB[dt] = f32x4{0.f, 0.f, 0.f, 0.f};
    }
    lA = f32x4{0.f, 0.f, 0.f, 0.f};
    lB = f32x4{0.f, 0.f, 0.f, 0.f};

    bf16x8 ones;
    #pragma unroll
    for (int i = 0; i < 8; ++i) ones[i] = (short)0x3F80;  // bf16 1.0

    // exp2 + pack + b64-write one strip's S^T tiles into Pl
    auto emitP = [&](const f32x4* sT, int sIdx, bool diag) {
        #pragma unroll
        for (int nt = 0; nt < 4; ++nt) {
            float e[4];
            #pragma unroll
            for (int r = 0; r < 4; ++r) {
                float xv = sT[nt][r];
                if (diag) {
                    const int tl = nt * 16 + quad * 4 + r;   // t within tile
                    xv = (tl <= wave * 16 + m16) ? xv : -1e30f;
                }
                e[r] = __builtin_exp2f(xv);
            }
            int2 dd;
            dd.x = pack2(e[0], e[1]);
            dd.y = pack2(e[2], e[3]);
            *(int2*)&Pl[wave][sIdx][m16][nt * PNT + quad * 4] = dd;
        }
    };
    // read P A-frag: P[m16][t = ks*32 + quad*8 + j]
    auto ldP = [&](int sIdx, int ks) -> bf16x8 {
        const short* pb = &Pl[wave][sIdx][m16]
                             [(2 * ks + (quad >> 1)) * PNT + (quad & 1) * 8];
        bf16x8 r;
        *(short4*)&r       = *(const short4*)pb;
        *((short4*)&r + 1) = *(const short4*)(pb + 4);
        return r;
    };

    loadTile(0);
    for (int it = 0; it <= tb; ++it) {
        const bool doA = (it <= ta);     // wave-uniform

        __syncthreads();                 // previous iteration done reading LDS
        *(bf16x8*)&Kl[kr0][kc0]      = rK[0];
        *(bf16x8*)&Kl[kr0 + 32][kc0] = rK[1];
        *(bf16x8*)&Vt[kr0][kc0]      = rV[0];
        *(bf16x8*)&Vt[kr0 + 32][kc0] = rV[1];
        __syncthreads();
        if (it < tb) loadTile((it + 1) * KT);  // in flight across compute

        // ---- S^T = K (Q/8·log2e)^T : same frags, swapped operands ----
        f32x4 sA[4], sB[4];
        #pragma unroll
        for (int nt = 0; nt < 4; ++nt) {
            bf16x8 k0 = *(const bf16x8*)&Kl[nt * 16 + m16][quad * 8];
            bf16x8 k1 = *(const bf16x8*)&Kl[nt * 16 + m16][32 + quad * 8];
            f32x4 z = {0.f, 0.f, 0.f, 0.f};
            f32x4 accb = __builtin_amdgcn_mfma_f32_16x16x32_bf16(k0, qB[0], z, 0, 0, 0);
            sB[nt] = __builtin_amdgcn_mfma_f32_16x16x32_bf16(k1, qB[1], accb, 0, 0, 0);
            if (doA) {
                f32x4 acca = __builtin_amdgcn_mfma_f32_16x16x32_bf16(k0, qA[0], z, 0, 0, 0);
                sA[nt] = __builtin_amdgcn_mfma_f32_16x16x32_bf16(k1, qA[1], acca, 0, 0, 0);
            }
        }

        // ---- exp2 + pack + P->LDS (b64 writes; no barrier: per-wave buffer) ----
        emitP(sB, 1, it == tb);
        if (doA) emitP(sA, 0, it == ta);

        // ---- O += P V ; l += P*1. V frags read once, feed both strips ----
        #pragma unroll
        for (int ks = 0; ks < 2; ++ks) {
            bf16x8 paB = ldP(1, ks);
            bf16x8 paA;
            if (doA) paA = ldP(0, ks);
            lB = __builtin_amdgcn_mfma_f32_16x16x32_bf16(paB, ones, lB, 0, 0, 0);
            if (doA) lA = __builtin_amdgcn_mfma_f32_16x16x32_bf16(paA, ones, lA, 0, 0, 0);
            #pragma unroll
            for (int dt = 0; dt < 4; ++dt) {
                bf16x8 vf = *(const bf16x8*)&Vt[dt * 16 + m16][ks * 32 + quad * 8];
                oB[dt] = __builtin_amdgcn_mfma_f32_16x16x32_bf16(paB, vf, oB[dt], 0, 0, 0);
                if (doA)
                    oA[dt] = __builtin_amdgcn_mfma_f32_16x16x32_bf16(paA, vf, oA[dt], 0, 0, 0);
            }
        }
    }

    // ---- epilogue: normalize, store fp32, both strips ----
    #pragma unroll
    for (int s = 0; s < 2; ++s) {
        const int tile = s ? tb : ta;
        #pragma unroll
        for (int r = 0; r < 4; ++r) {
            const float inv = 1.f / (s ? lB[r] : lA[r]);
            const int srow  = tile * 64 + wave * 16 + quad * 4 + r;
            float* op = Out + (size_t)srow * SROW + bh * D;
            #pragma unroll
            for (int dt = 0; dt < 4; ++dt)
                op[dt * 16 + m16] = (s ? oB[dt][r] : oA[dt][r]) * inv;
        }
    }
}

extern "C" void kernel_launch(void* const* d_in, const int* in_sizes, int n_in,
                              void* d_out, int out_size, void* d_ws, size_t ws_size,
                              hipStream_t stream) {
    const float* Q = (const float*)d_in[0];
    const float* K = (const float*)d_in[1];
    const float* V = (const float*)d_in[2];
    // d_in[3] (attention_mask) is pure causal — folded into the kernel.
    float* Out = (float*)d_out;

    // d_ws layout: Kb | Vb (bf16), 8 MB each
    short* Kb = (short*)d_ws;
    short* Vb = Kb + (size_t)BH * PLANE;

    dim3 gcvt(SQ / 64, BH);
    cvt<<<gcvt, 256, 0, stream>>>(K, V, Kb, Vb);
    attn_fwd<<<dim3(512), 256, 0, stream>>>(Q, Kb, Vb, Out);
}

// Round 6
// 151.049 us; speedup vs baseline: 1.0447x; 1.0447x over previous
//
#include <hip/hip_runtime.h>
#include <hip/hip_bf16.h>

typedef __attribute__((ext_vector_type(8))) short bf16x8;
typedef __attribute__((ext_vector_type(4))) float f32x4;

constexpr int SQ = 2048;
constexpr int NB = 2;
constexpr int NH = 16;
constexpr int D  = 64;
constexpr int SROW = NB * NH * D;        // 2048 floats per s step (layout s,b,h,d)
constexpr int BH   = NB * NH;            // 32 (b,h) planes
constexpr int KT = 64;                   // kv cols per tile
constexpr int LDP = 72;                  // K/V LDS leading dim (shorts); b128-balanced
constexpr int PST = 68;                  // P row stride in shorts: 136 B == 2 banks/row
                                         // -> 16 m16-rows walk all 32 banks per phase
constexpr size_t PLANE = (size_t)SQ * D; // 131072 shorts per (b,h) plane

// scale folded into Q: 1/sqrt(64) (coeff cancels) * log2(e) so exp2() is direct
constexpr float QSCALE = 0.125f * 1.44269504088896f;

// pack two fp32 -> bf16x2 dword (round-half-up; differs from RNE only on ties)
__device__ __forceinline__ int pack2(float lo, float hi) {
    unsigned ul = __builtin_bit_cast(unsigned, lo) + 0x8000u;
    unsigned uh = __builtin_bit_cast(unsigned, hi) + 0x8000u;
    return __builtin_amdgcn_perm(uh, ul, 0x07060302);  // {hi.b3,hi.b2,lo.b3,lo.b2}
}

// ---------------------------------------------------------------------------
// Pre-kernel: K, V fp32 -> bf16 with layout change (amortized over ~16 re-reads)
//   Kb[bh][s][d] = bf16(K)
//   Vb[bh][d][s] = bf16(V)^T
// ---------------------------------------------------------------------------
__global__ __launch_bounds__(256)
void cvt(const float* __restrict__ K, const float* __restrict__ V,
         short* __restrict__ Kb, short* __restrict__ Vb) {
    __shared__ short Vl[64][LDP];
    const int tid = threadIdx.x;
    const int t0  = blockIdx.x * 64;
    const int bh  = blockIdx.y;
    const int r   = tid >> 2;
    const int c   = (tid & 3) * 16;

    const size_t gin  = (size_t)(t0 + r) * SROW + bh * D + c;
    const size_t gout = (size_t)bh * PLANE + (size_t)(t0 + r) * D + c;

    {   // K: convert, same layout
        const float* kp = K + gin;
        int o[8];
        #pragma unroll
        for (int i = 0; i < 8; ++i) o[i] = pack2(kp[2 * i], kp[2 * i + 1]);
        *(int4*)&Kb[gout]     = *(int4*)&o[0];
        *(int4*)&Kb[gout + 8] = *(int4*)&o[4];
    }
    {   // V: convert into LDS, transpose out
        const float* vp = V + gin;
        int o[8];
        #pragma unroll
        for (int i = 0; i < 8; ++i) o[i] = pack2(vp[2 * i], vp[2 * i + 1]);
        *(int4*)&Vl[r][c]     = *(int4*)&o[0];
        *(int4*)&Vl[r][c + 8] = *(int4*)&o[4];
    }
    __syncthreads();
    {
        const int d = tid & 63, seg = tid >> 6;
        short t[16];
        #pragma unroll
        for (int u = 0; u < 16; ++u) t[u] = Vl[seg * 16 + u][d];
        const size_t vo = (size_t)bh * PLANE + (size_t)d * SQ + t0 + seg * 16;
        *(bf16x8*)&Vb[vo]     = *(bf16x8*)&t[0];
        *(bf16x8*)&Vb[vo + 8] = *(bf16x8*)&t[8];
    }
}

// ---------------------------------------------------------------------------
// Hot kernel: LDS-staged causal flash attention, complementary q-tile pairing.
// R6 changes vs R5:
//  - P row stride 80 -> 68 shorts (136 B == 2 banks): per half-wave phase every
//    bank gets exactly the minimum load for the b64 P writes/reads (the R5
//    stride of 160 B == 8 banks left half the banks idle -> 2x conflicts).
//  - K/V LDS double-buffered: staging writes for tile i+1 go to the other
//    buffer after compute on tile i -> ONE barrier per iteration (was two),
//    and the prefetch loads get the whole compute phase to land.
// ---------------------------------------------------------------------------
__global__ __launch_bounds__(256, 2)
void attn_fwd(const float* __restrict__ Q, const short* __restrict__ Kb,
              const short* __restrict__ Vb, float* __restrict__ Out) {
    __shared__ short Kl[2][KT][LDP];        // K[t][d], double-buffered
    __shared__ short Vt[2][D][LDP];         // V^T[d][t], double-buffered
    __shared__ short Pl[4][2][16][PST];     // [wave][strip][m][t] bf16

    const int tid  = threadIdx.x;
    const int wave = tid >> 6;
    const int m16  = tid & 15;
    const int quad = (tid & 63) >> 4;

    // decode: CU c gets blocks c (a = c%16) and c+256 (a = 15 - c%16)
    // -> per-CU iteration total is a constant 49
    const int x    = blockIdx.x;
    const int pr   = x & 255;
    const int half = x >> 8;
    const int bh   = (pr >> 4) | (half << 4);
    const int ta   = half ? (15 - (pr & 15)) : (pr & 15);
    const int tb   = 31 - ta;
    const size_t plane = (size_t)bh * PLANE;

    // ---- Q fragments (fp32 -> bf16, scale = 1/8 * log2e) ----
    bf16x8 qA[2], qB[2];
    #pragma unroll
    for (int s = 0; s < 2; ++s) {
        const int tile = s ? tb : ta;
        const float* qp = Q + (size_t)(tile * 64 + wave * 16 + m16) * SROW
                            + bh * D + quad * 8;
        #pragma unroll
        for (int ks = 0; ks < 2; ++ks) {
            float4 x0 = *(const float4*)(qp + ks * 32);
            float4 x1 = *(const float4*)(qp + ks * 32 + 4);
            int o[4];
            o[0] = pack2(x0.x * QSCALE, x0.y * QSCALE);
            o[1] = pack2(x0.z * QSCALE, x0.w * QSCALE);
            o[2] = pack2(x1.x * QSCALE, x1.y * QSCALE);
            o[3] = pack2(x1.z * QSCALE, x1.w * QSCALE);
            bf16x8 f = *(bf16x8*)&o[0];
            if (s) qB[ks] = f; else qA[ks] = f;
        }
    }

    const short* kb = Kb + plane;
    const short* vb = Vb + plane;

    // staging: thread owns 2 b128 chunks of K and 2 of V per tile
    const int kr0 = tid >> 3;            // rows 0..31
    const int kc0 = (tid & 7) * 8;
    bf16x8 rK[2], rV[2];
    auto loadTile = [&](int t0) {
        const short* kt = kb + (size_t)t0 * D;
        rK[0] = *(const bf16x8*)(kt + (size_t)kr0 * D + kc0);
        rK[1] = *(const bf16x8*)(kt + (size_t)(kr0 + 32) * D + kc0);
        const short* vt = vb + t0;
        rV[0] = *(const bf16x8*)(vt + (size_t)kr0 * SQ + kc0);
        rV[1] = *(const bf16x8*)(vt + (size_t)(kr0 + 32) * SQ + kc0);
    };
    auto stage = [&](int buf) {
        *(bf16x8*)&Kl[buf][kr0][kc0]      = rK[0];
        *(bf16x8*)&Kl[buf][kr0 + 32][kc0] = rK[1];
        *(bf16x8*)&Vt[buf][kr0][kc0]      = rV[0];
        *(bf16x8*)&Vt[buf][kr0 + 32][kc0] = rV[1];
    };

    f32x4 oA[4], oB[4], lA, lB;
    #pragma unroll
    for (int dt = 0; dt < 4; ++dt) {
        oA[dt] = f32x4{0.f, 0.f, 0.f, 0.f};
        oB[dt] = f32x4{0.f, 0.f, 0.f, 0.f};
    }
    lA = f32x4{0.f, 0.f, 0.f, 0.f};
    lB = f32x4{0.f, 0.f, 0.f, 0.f};

    bf16x8 ones;
    #pragma unroll
    for (int i = 0; i < 8; ++i) ones[i] = (short)0x3F80;  // bf16 1.0

    // exp2 + pack + b64-write one strip's S^T tiles into Pl (t-major row)
    auto emitP = [&](const f32x4* sT, int sIdx, bool diag) {
        #pragma unroll
        for (int nt = 0; nt < 4; ++nt) {
            float e[4];
            #pragma unroll
            for (int r = 0; r < 4; ++r) {
                float xv = sT[nt][r];
                if (diag) {
                    const int tl = nt * 16 + quad * 4 + r;   // t within tile
                    xv = (tl <= wave * 16 + m16) ? xv : -1e30f;
                }
                e[r] = __builtin_exp2f(xv);
            }
            int2 dd;
            dd.x = pack2(e[0], e[1]);
            dd.y = pack2(e[2], e[3]);
            *(int2*)&Pl[wave][sIdx][m16][nt * 16 + quad * 4] = dd;
        }
    };
    // read P A-frag: P[m16][t = ks*32 + quad*8 + j]
    auto ldP = [&](int sIdx, int ks) -> bf16x8 {
        const short* pb = &Pl[wave][sIdx][m16][ks * 32 + quad * 8];
        bf16x8 r;
        *(short4*)&r       = *(const short4*)pb;
        *((short4*)&r + 1) = *(const short4*)(pb + 4);
        return r;
    };

    loadTile(0);
    stage(0);
    __syncthreads();

    for (int it = 0; it <= tb; ++it) {
        const int  cur = it & 1;
        const bool doA = (it <= ta);     // wave-uniform
        if (it < tb) loadTile((it + 1) * KT);  // in flight across compute

        // ---- S^T = K (Q/8·log2e)^T : same frags, swapped operands ----
        f32x4 sA[4], sB[4];
        #pragma unroll
        for (int nt = 0; nt < 4; ++nt) {
            bf16x8 k0 = *(const bf16x8*)&Kl[cur][nt * 16 + m16][quad * 8];
            bf16x8 k1 = *(const bf16x8*)&Kl[cur][nt * 16 + m16][32 + quad * 8];
            f32x4 z = {0.f, 0.f, 0.f, 0.f};
            f32x4 accb = __builtin_amdgcn_mfma_f32_16x16x32_bf16(k0, qB[0], z, 0, 0, 0);
            sB[nt] = __builtin_amdgcn_mfma_f32_16x16x32_bf16(k1, qB[1], accb, 0, 0, 0);
            if (doA) {
                f32x4 acca = __builtin_amdgcn_mfma_f32_16x16x32_bf16(k0, qA[0], z, 0, 0, 0);
                sA[nt] = __builtin_amdgcn_mfma_f32_16x16x32_bf16(k1, qA[1], acca, 0, 0, 0);
            }
        }

        // ---- exp2 + pack + P->LDS (b64; per-wave buffer, no barrier) ----
        emitP(sB, 1, it == tb);
        if (doA) emitP(sA, 0, it == ta);

        // ---- O += P V ; l += P*1. V frags read once, feed both strips ----
        #pragma unroll
        for (int ks = 0; ks < 2; ++ks) {
            bf16x8 paB = ldP(1, ks);
            bf16x8 paA;
            if (doA) paA = ldP(0, ks);
            lB = __builtin_amdgcn_mfma_f32_16x16x32_bf16(paB, ones, lB, 0, 0, 0);
            if (doA) lA = __builtin_amdgcn_mfma_f32_16x16x32_bf16(paA, ones, lA, 0, 0, 0);
            #pragma unroll
            for (int dt = 0; dt < 4; ++dt) {
                bf16x8 vf = *(const bf16x8*)&Vt[cur][dt * 16 + m16][ks * 32 + quad * 8];
                oB[dt] = __builtin_amdgcn_mfma_f32_16x16x32_bf16(paB, vf, oB[dt], 0, 0, 0);
                if (doA)
                    oA[dt] = __builtin_amdgcn_mfma_f32_16x16x32_bf16(paA, vf, oA[dt], 0, 0, 0);
            }
        }

        // ---- stage next tile into the other buffer; single barrier ----
        if (it < tb) stage(cur ^ 1);
        __syncthreads();
    }

    // ---- epilogue: normalize, store fp32, both strips ----
    #pragma unroll
    for (int s = 0; s < 2; ++s) {
        const int tile = s ? tb : ta;
        #pragma unroll
        for (int r = 0; r < 4; ++r) {
            const float inv = 1.f / (s ? lB[r] : lA[r]);
            const int srow  = tile * 64 + wave * 16 + quad * 4 + r;
            float* op = Out + (size_t)srow * SROW + bh * D;
            #pragma unroll
            for (int dt = 0; dt < 4; ++dt)
                op[dt * 16 + m16] = (s ? oB[dt][r] : oA[dt][r]) * inv;
        }
    }
}

extern "C" void kernel_launch(void* const* d_in, const int* in_sizes, int n_in,
                              void* d_out, int out_size, void* d_ws, size_t ws_size,
                              hipStream_t stream) {
    const float* Q = (const float*)d_in[0];
    const float* K = (const float*)d_in[1];
    const float* V = (const float*)d_in[2];
    // d_in[3] (attention_mask) is pure causal — folded into the kernel.
    float* Out = (float*)d_out;

    // d_ws layout: Kb | Vb (bf16), 8 MB each
    short* Kb = (short*)d_ws;
    short* Vb = Kb + (size_t)BH * PLANE;

    dim3 gcvt(SQ / 64, BH);
    cvt<<<gcvt, 256, 0, stream>>>(K, V, Kb, Vb);
    attn_fwd<<<dim3(512), 256, 0, stream>>>(Q, Kb, Vb, Out);
}

// Round 7
// 139.462 us; speedup vs baseline: 1.1315x; 1.0831x over previous
//
#include <hip/hip_runtime.h>
#include <hip/hip_bf16.h>

typedef __attribute__((ext_vector_type(8))) short bf16x8;
typedef __attribute__((ext_vector_type(4))) float f32x4;

constexpr int SQ = 2048;
constexpr int NB = 2;
constexpr int NH = 16;
constexpr int D  = 64;
constexpr int SROW = NB * NH * D;        // 2048 floats per s step (layout s,b,h,d)
constexpr int BH   = NB * NH;            // 32 (b,h) planes
constexpr int LDP = 72;                  // cvt LDS leading dim (shorts)
constexpr int PST = 68;                  // P row stride (136 B == 2 banks/row, 8B-aligned)
constexpr int TCH = 4096;                // shorts per 64x64 bf16 tile
constexpr size_t PLANE = (size_t)SQ * D; // 131072 shorts per (b,h) plane

// scale folded into Q: 1/sqrt(64) (coeff cancels) * log2(e) so exp2() is direct
constexpr float QSCALE = 0.125f * 1.44269504088896f;

// pack two fp32 -> bf16x2 dword (round-half-up; differs from RNE only on ties)
__device__ __forceinline__ int pack2(float lo, float hi) {
    unsigned ul = __builtin_bit_cast(unsigned, lo) + 0x8000u;
    unsigned uh = __builtin_bit_cast(unsigned, hi) + 0x8000u;
    return __builtin_amdgcn_perm(uh, ul, 0x07060302);  // {hi.b3,hi.b2,lo.b3,lo.b2}
}

// ---------------------------------------------------------------------------
// Pre-kernel: K, V fp32 -> bf16 in MFMA-FRAGMENT order, so the hot kernel
// reads each fragment as ONE coalesced global b128 (lane i <- base + 16 B * i).
//   Per 64x64 tile, 512 chunks of 8 shorts:
//   K chunk (ks+2*nt)*64 + lane  holds K[nt*16+(lane&15)][ks*32+(lane>>4)*8 ..+7]
//   V chunk (ks+2*dt)*64 + lane  holds V^T[dt*16+(lane&15)][ks*32+(lane>>4)*8 ..+7]
// ---------------------------------------------------------------------------
__global__ __launch_bounds__(256)
void cvt(const float* __restrict__ K, const float* __restrict__ V,
         short* __restrict__ Kf, short* __restrict__ Vf) {
    __shared__ short Vl[64][LDP];
    const int tid  = threadIdx.x;
    const int tile = blockIdx.x;
    const int bh   = blockIdx.y;
    const int t0   = tile * 64;

    {   // stage V tile into LDS bf16 (t-major), coalesced fp32 reads
        const int r = tid >> 2, c = (tid & 3) * 16;
        const float* vp = V + (size_t)(t0 + r) * SROW + bh * D + c;
        int o[8];
        #pragma unroll
        for (int i = 0; i < 8; ++i) o[i] = pack2(vp[2 * i], vp[2 * i + 1]);
        *(int4*)&Vl[r][c]     = *(int4*)&o[0];
        *(int4*)&Vl[r][c + 8] = *(int4*)&o[4];
    }

    {   // K fragment chunks straight from global
        short* kout = Kf + (size_t)bh * PLANE + (size_t)tile * TCH;
        #pragma unroll
        for (int cc = tid; cc < 512; cc += 256) {
            const int g   = cc >> 6, ln = cc & 63;
            const int row = (g >> 1) * 16 + (ln & 15);
            const int col = (g & 1) * 32 + (ln >> 4) * 8;
            const float* kp = K + (size_t)(t0 + row) * SROW + bh * D + col;
            float4 x0 = *(const float4*)kp;
            float4 x1 = *(const float4*)(kp + 4);
            int o[4];
            o[0] = pack2(x0.x, x0.y); o[1] = pack2(x0.z, x0.w);
            o[2] = pack2(x1.x, x1.y); o[3] = pack2(x1.z, x1.w);
            *(int4*)&kout[cc * 8] = *(int4*)o;
        }
    }
    __syncthreads();
    {   // V^T fragment chunks via the LDS transpose
        short* vout = Vf + (size_t)bh * PLANE + (size_t)tile * TCH;
        #pragma unroll
        for (int cc = tid; cc < 512; cc += 256) {
            const int g  = cc >> 6, ln = cc & 63;
            const int d  = (g >> 1) * 16 + (ln & 15);
            const int tr = (g & 1) * 32 + (ln >> 4) * 8;
            short t[8];
            #pragma unroll
            for (int j = 0; j < 8; ++j) t[j] = Vl[tr + j][d];
            *(int4*)&vout[cc * 8] = *(int4*)t;
        }
    }
}

// ---------------------------------------------------------------------------
// Hot kernel: barrier-free causal flash attention, fragment-order global K/V.
//  - K/V fragments load directly from global (one b128 per fragment, perfectly
//    coalesced). All 4 waves + the paired same-bh block read identical
//    addresses -> L1 serves the replication (2 tiles = 16 KB << 32 KB L1).
//  - Software prefetch: K-frags for tile i+1 issued right after the S-MFMAs,
//    V-frags after PV -> a full compute phase of latency tolerance (this is
//    what R3 lacked).
//  - No __syncthreads at all; LDS carries only the per-wave P roundtrip.
//  - Complementary pairing {a, 31-a} kept: constant 49 iters per CU.
// ---------------------------------------------------------------------------
__global__ __launch_bounds__(256, 2)
void attn_fwd(const float* __restrict__ Q, const short* __restrict__ Kf,
              const short* __restrict__ Vf, float* __restrict__ Out) {
    __shared__ short Pl[4][2][16][PST];     // [wave][strip][m][t] bf16

    const int tid  = threadIdx.x;
    const int wave = tid >> 6;
    const int lane = tid & 63;
    const int m16  = tid & 15;
    const int quad = (tid & 63) >> 4;

    // decode: CU c gets blocks c (a = c>>5) and c+256 (a = 15 - (c>>5)),
    // same bh = c&31 -> paired blocks share K/V tiles in L1/L2.
    const int c  = blockIdx.x & 255;
    const int qh = blockIdx.x >> 8;
    const int u  = c >> 5;
    const int bh = c & 31;
    const int ta = qh ? (15 - u) : u;
    const int tb = 31 - ta;

    // ---- Q fragments (fp32 -> bf16, scale = 1/8 * log2e) ----
    bf16x8 qA[2], qB[2];
    #pragma unroll
    for (int s = 0; s < 2; ++s) {
        const int tile = s ? tb : ta;
        const float* qp = Q + (size_t)(tile * 64 + wave * 16 + m16) * SROW
                            + bh * D + quad * 8;
        #pragma unroll
        for (int ks = 0; ks < 2; ++ks) {
            float4 x0 = *(const float4*)(qp + ks * 32);
            float4 x1 = *(const float4*)(qp + ks * 32 + 4);
            int o[4];
            o[0] = pack2(x0.x * QSCALE, x0.y * QSCALE);
            o[1] = pack2(x0.z * QSCALE, x0.w * QSCALE);
            o[2] = pack2(x1.x * QSCALE, x1.y * QSCALE);
            o[3] = pack2(x1.z * QSCALE, x1.w * QSCALE);
            bf16x8 f = *(bf16x8*)&o[0];
            if (s) qB[ks] = f; else qA[ks] = f;
        }
    }

    const short* kb = Kf + (size_t)bh * PLANE;
    const short* vb = Vf + (size_t)bh * PLANE;
    auto ldK = [&](int t, int j) -> bf16x8 {
        return *(const bf16x8*)(kb + (size_t)t * TCH + j * 512 + lane * 8);
    };
    auto ldV = [&](int t, int j) -> bf16x8 {
        return *(const bf16x8*)(vb + (size_t)t * TCH + j * 512 + lane * 8);
    };

    f32x4 oA[4], oB[4], lA, lB;
    #pragma unroll
    for (int dt = 0; dt < 4; ++dt) {
        oA[dt] = f32x4{0.f, 0.f, 0.f, 0.f};
        oB[dt] = f32x4{0.f, 0.f, 0.f, 0.f};
    }
    lA = f32x4{0.f, 0.f, 0.f, 0.f};
    lB = f32x4{0.f, 0.f, 0.f, 0.f};

    bf16x8 ones;
    #pragma unroll
    for (int i = 0; i < 8; ++i) ones[i] = (short)0x3F80;  // bf16 1.0

    // exp2 + pack + b64-write one strip's S^T tiles into Pl
    auto emitP = [&](const f32x4* sT, int sIdx, bool diag) {
        #pragma unroll
        for (int nt = 0; nt < 4; ++nt) {
            float e[4];
            #pragma unroll
            for (int r = 0; r < 4; ++r) {
                float xv = sT[nt][r];
                if (diag) {
                    const int tl = nt * 16 + quad * 4 + r;   // t within tile
                    xv = (tl <= wave * 16 + m16) ? xv : -1e30f;
                }
                e[r] = __builtin_exp2f(xv);
            }
            int2 dd;
            dd.x = pack2(e[0], e[1]);
            dd.y = pack2(e[2], e[3]);
            *(int2*)&Pl[wave][sIdx][m16][nt * 16 + quad * 4] = dd;
        }
    };
    // read P A-frag: P[m16][t = ks*32 + quad*8 + j]
    auto ldP = [&](int sIdx, int ks) -> bf16x8 {
        const short* pb = &Pl[wave][sIdx][m16][ks * 32 + quad * 8];
        bf16x8 r;
        *(short4*)&r       = *(const short4*)pb;
        *((short4*)&r + 1) = *(const short4*)(pb + 4);
        return r;
    };

    // prologue: fragments for tile 0
    bf16x8 kf[8], vf[8];
    #pragma unroll
    for (int j = 0; j < 8; ++j) { kf[j] = ldK(0, j); vf[j] = ldV(0, j); }

    for (int it = 0; it <= tb; ++it) {
        const bool doA = (it <= ta);     // wave-uniform

        // ---- S^T = K (Q/8·log2e)^T from register fragments ----
        f32x4 sA[4], sB[4];
        #pragma unroll
        for (int nt = 0; nt < 4; ++nt) {
            bf16x8 k0 = kf[2 * nt];
            bf16x8 k1 = kf[2 * nt + 1];
            f32x4 z = {0.f, 0.f, 0.f, 0.f};
            f32x4 accb = __builtin_amdgcn_mfma_f32_16x16x32_bf16(k0, qB[0], z, 0, 0, 0);
            sB[nt] = __builtin_amdgcn_mfma_f32_16x16x32_bf16(k1, qB[1], accb, 0, 0, 0);
            if (doA) {
                f32x4 acca = __builtin_amdgcn_mfma_f32_16x16x32_bf16(k0, qA[0], z, 0, 0, 0);
                sA[nt] = __builtin_amdgcn_mfma_f32_16x16x32_bf16(k1, qA[1], acca, 0, 0, 0);
            }
        }

        // ---- prefetch K fragments for tile it+1 (K regs just freed) ----
        if (it < tb) {
            #pragma unroll
            for (int j = 0; j < 8; ++j) kf[j] = ldK(it + 1, j);
        }

        // ---- exp2 + pack + P->LDS (per-wave buffer, in-wave ordering) ----
        emitP(sB, 1, it == tb);
        if (doA) emitP(sA, 0, it == ta);

        // ---- O += P V ; l += P*1 ----
        #pragma unroll
        for (int ks = 0; ks < 2; ++ks) {
            bf16x8 paB = ldP(1, ks);
            bf16x8 paA;
            if (doA) paA = ldP(0, ks);
            lB = __builtin_amdgcn_mfma_f32_16x16x32_bf16(paB, ones, lB, 0, 0, 0);
            if (doA) lA = __builtin_amdgcn_mfma_f32_16x16x32_bf16(paA, ones, lA, 0, 0, 0);
            #pragma unroll
            for (int dt = 0; dt < 4; ++dt) {
                bf16x8 vv = vf[2 * dt + ks];
                oB[dt] = __builtin_amdgcn_mfma_f32_16x16x32_bf16(paB, vv, oB[dt], 0, 0, 0);
                if (doA)
                    oA[dt] = __builtin_amdgcn_mfma_f32_16x16x32_bf16(paA, vv, oA[dt], 0, 0, 0);
            }
        }

        // ---- prefetch V fragments for tile it+1 (V regs just freed) ----
        if (it < tb) {
            #pragma unroll
            for (int j = 0; j < 8; ++j) vf[j] = ldV(it + 1, j);
        }
    }

    // ---- epilogue: normalize, store fp32, both strips ----
    #pragma unroll
    for (int s = 0; s < 2; ++s) {
        const int tile = s ? tb : ta;
        #pragma unroll
        for (int r = 0; r < 4; ++r) {
            const float inv = 1.f / (s ? lB[r] : lA[r]);
            const int srow  = tile * 64 + wave * 16 + quad * 4 + r;
            float* op = Out + (size_t)srow * SROW + bh * D;
            #pragma unroll
            for (int dt = 0; dt < 4; ++dt)
                op[dt * 16 + m16] = (s ? oB[dt][r] : oA[dt][r]) * inv;
        }
    }
}

extern "C" void kernel_launch(void* const* d_in, const int* in_sizes, int n_in,
                              void* d_out, int out_size, void* d_ws, size_t ws_size,
                              hipStream_t stream) {
    const float* Q = (const float*)d_in[0];
    const float* K = (const float*)d_in[1];
    const float* V = (const float*)d_in[2];
    // d_in[3] (attention_mask) is pure causal — folded into the kernel.
    float* Out = (float*)d_out;

    // d_ws layout: Kf | Vf (bf16, fragment order), 8 MB each
    short* Kf = (short*)d_ws;
    short* Vf = Kf + (size_t)BH * PLANE;

    dim3 gcvt(SQ / 64, BH);
    cvt<<<gcvt, 256, 0, stream>>>(K, V, Kf, Vf);
    attn_fwd<<<dim3(512), 256, 0, stream>>>(Q, Kf, Vf, Out);
}